// Round 7
// baseline (85.158 us; speedup 1.0000x reference)
//
#include <hip/hip_runtime.h>
#include <hip/hip_bf16.h>
#include <math.h>

#define B_N   256
#define EMB_N 512
#define CLS_N 20000
#define NMB   157          // class tiles of 128 (157*128 = 20096 >= 20000)
#define PI_F  3.14159265f
#define F_CONST ((float)(1.1 / 1501.1))

typedef __bf16 bf16x8 __attribute__((ext_vector_type(8)));
typedef float  f32x4  __attribute__((ext_vector_type(4)));
typedef unsigned short u16x8 __attribute__((ext_vector_type(8)));

__device__ __forceinline__ unsigned short f2bf(float f) {
    unsigned u = __float_as_uint(f);
    unsigned r = (u + 0x7FFFu + ((u >> 16) & 1u)) >> 16;  // RNE
    return (unsigned short)r;
}

__device__ __forceinline__ void merge4(float& M, float& S, float& VM, int& VI,
                                       float m2, float s2, float vm2, int vi2) {
    float mn = fmaxf(M, m2);
    if (mn == -INFINITY) { S = 0.f; }
    else S = S * __expf(M - mn) + s2 * __expf(m2 - mn);
    M = mn;
    if (vm2 > VM || (vm2 == VM && vi2 < VI)) { VM = vm2; VI = vi2; }
}

// ---------------- prep: per-row scalars + bf16 stacked batch operand ----------------
__global__ __launch_bounds__(256) void prep_kernel(
    const float* __restrict__ emb, const int* __restrict__ y,
    const float* __restrict__ W,
    unsigned short* __restrict__ Abf,
    float* __restrict__ xlen_a, float* __restrict__ inv_xlen_a,
    float* __restrict__ inv_wny_a, float* __restrict__ mod_val_a)
{
    const int b = blockIdx.x;
    const int t = threadIdx.x;
    const int yb = y[b];
    const float* erow = emb + (size_t)b * EMB_N;
    float se = 0.f, sw = 0.f, dt = 0.f;
    for (int e = t; e < EMB_N; e += 256) {
        float ev = erow[e];
        float wv = W[(size_t)e * CLS_N + yb];
        Abf[(size_t)b * EMB_N + e]         = f2bf(ev);
        Abf[(size_t)(B_N + b) * EMB_N + e] = f2bf(wv);
        se += ev * ev; sw += wv * wv; dt += ev * wv;
    }
    __shared__ float r0[256], r1[256], r2[256];
    r0[t] = se; r1[t] = sw; r2[t] = dt;
    __syncthreads();
    for (int s = 128; s > 0; s >>= 1) {
        if (t < s) { r0[t] += r0[t + s]; r1[t] += r1[t + s]; r2[t] += r2[t + s]; }
        __syncthreads();
    }
    if (t == 0) {
        float xlen = sqrtf(r0[0]);
        float wn   = sqrtf(r1[0]);
        float inv_x = 1.f / xlen;
        float inv_w = 1.f / wn;
        float cos_t = r2[0] * inv_w * inv_x;
        cos_t = fminf(1.f, fmaxf(-1.f, cos_t));
        float c2 = cos_t * cos_t;
        float cos_m = 8.f * c2 * c2 - 8.f * c2 + 1.f;
        float theta = acosf(cos_t);
        float k = floorf(4.f * theta / PI_F);
        float sgn = 1.f - 2.f * fmodf(k, 2.f);
        float phi = sgn * cos_m - 2.f * k;
        float cos_s = cos_t * xlen;
        float phi_s = phi * xlen;
        xlen_a[b] = xlen;
        inv_xlen_a[b] = inv_x;
        inv_wny_a[b] = inv_w;
        mod_val_a[b] = cos_s + F_CONST * (phi_s - cos_s);
    }
}

// ---------------- fused MFMA GEMM ----------------
// Tile: 128 classes (M, from fp32 W transposed in-register) x 64 batch (N, bf16 Abf).
// 4 waves (2M x 2N): wave = 64c x 32b, acc[4][2] f32x4. BK=64, 8 K-steps.
// Swizzle key ((row>>1)&7) on 16B quads for A-write/A-read/B-DMA-src/B-read.
__global__ __launch_bounds__(256) void mfma_gemm_kernel(
    const float* __restrict__ W, const unsigned short* __restrict__ Abf,
    const int* __restrict__ y,
    const float* __restrict__ xlen_a, const float* __restrict__ inv_xlen_a,
    const float* __restrict__ inv_wny_a,
    float* __restrict__ logits, float4* __restrict__ partials,
    float* __restrict__ inter_sum)
{
    __shared__ alignas(16) char smem[16384 + 16384];   // sA 16K | sB 2x8K
    char* sA = smem;
    char* sB0 = smem + 16384;
    // epilogue overlays (on sB[0] region, dead after the loop)
    float*  sSq   = (float*)sB0;             // [8][128] = 4 KB
    float*  sIwc  = (float*)(sB0 + 4096);    // 128 floats
    float4* sPart = (float4*)(sB0 + 4608);   // [64][2] = 2 KB
    float*  red   = (float*)(sB0 + 6656);    // 256 floats

    const int bid = blockIdx.x;
    const int g   = (bid & 7) * NMB + (bid >> 3);   // XCD-chunked (1256 = 8*157)
    const int m_blk = g >> 3;
    const int nb    = g & 7;            // 0..3: logits slices; 4..7: MHE slices
    const int m0    = m_blk * 128;      // class base
    const int gn0   = nb * 64;          // stacked-batch base (0..511)

    const int t    = threadIdx.x;
    const int lane = t & 63;
    const int wid  = t >> 6;
    const int wr   = wid >> 1;          // class half (64 rows)
    const int wc   = wid & 1;           // batch half (32 cols)
    const int r16  = lane & 15;
    const int kh   = lane >> 4;

    const char* Bb = (const char*)Abf;

    f32x4 acc[4][2] = {};
    f32x4 areg[8];
    float ssq[4] = {0.f, 0.f, 0.f, 0.f};

    // A staging: thread = 4 classes (cg*4..+3) x 8 k's (k8*8..+7)
    const int cg  = t & 31;
    const int k8  = t >> 5;
    const int gc4 = min(m0 + cg * 4, CLS_N - 4);   // clamped; tail masked later

    #define BARRIER_FENCED()                                   \
        { __builtin_amdgcn_sched_barrier(0);                   \
          asm volatile("s_barrier" ::: "memory");              \
          __builtin_amdgcn_sched_barrier(0); }

    #define ISSUE_A(kt)                                                           \
        { _Pragma("unroll")                                                       \
          for (int p = 0; p < 8; ++p)                                             \
              areg[p] = *reinterpret_cast<const f32x4*>(                          \
                  &W[(size_t)((kt) + k8 * 8 + p) * CLS_N + gc4]);                 \
        }

    #define ISSUE_B(kt, bufidx)                                                   \
        { _Pragma("unroll")                                                       \
          for (int i = 0; i < 2; ++i) {                                           \
              int slot = wid * 2 + i;                                             \
              int row  = slot * 8 + (lane >> 3);                                  \
              int key  = (slot * 4 + (lane >> 4)) & 7;                            \
              int srcq = (lane & 7) ^ key;                                        \
              __builtin_amdgcn_global_load_lds(                                   \
                  (const __attribute__((address_space(1))) unsigned int*)         \
                      (Bb + (size_t)(gn0 + row) * 1024 + (size_t)(kt) * 2         \
                          + srcq * 16),                                           \
                  (__attribute__((address_space(3))) unsigned int*)               \
                      (sB0 + (bufidx) * 8192 + slot * 1024),                      \
                  16, 0, 0);                                                      \
          } }

    #define WRITE_A()                                                             \
        { _Pragma("unroll")                                                       \
          for (int jj = 0; jj < 4; ++jj) {                                        \
              u16x8 u;                                                            \
              float sq = 0.f;                                                     \
              _Pragma("unroll")                                                   \
              for (int p = 0; p < 8; ++p) {                                       \
                  float v = areg[p][jj];                                          \
                  u[p] = f2bf(v);                                                 \
                  sq += v * v;                                                    \
              }                                                                   \
              ssq[jj] += sq;                                                      \
              int c = cg * 4 + jj;                                                \
              int byo = (c * 128 + k8 * 16) ^ (((c >> 1) & 7) << 4);              \
              *reinterpret_cast<u16x8*>(sA + byo) = u;                            \
          } }

    #define COMPUTE(bufidx)                                                       \
        { _Pragma("unroll")                                                       \
          for (int kk = 0; kk < 2; ++kk) {                                        \
              bf16x8 af[4], bfr[2];                                               \
              _Pragma("unroll")                                                   \
              for (int mi = 0; mi < 4; ++mi) {                                    \
                  int row = wr * 64 + mi * 16 + r16;                              \
                  int off = (row * 128 + kk * 64 + kh * 16)                       \
                            ^ (((row >> 1) & 7) << 4);                            \
                  af[mi] = *reinterpret_cast<const bf16x8*>(sA + off);            \
              }                                                                   \
              _Pragma("unroll")                                                   \
              for (int ni = 0; ni < 2; ++ni) {                                    \
                  int row = wc * 32 + ni * 16 + r16;                              \
                  int off = (row * 128 + kk * 64 + kh * 16)                       \
                            ^ (((row >> 1) & 7) << 4);                            \
                  bfr[ni] = *reinterpret_cast<const bf16x8*>(                     \
                      sB0 + (bufidx) * 8192 + off);                               \
              }                                                                   \
              _Pragma("unroll")                                                   \
              for (int mi = 0; mi < 4; ++mi)                                      \
                  _Pragma("unroll")                                               \
                  for (int ni = 0; ni < 2; ++ni)                                  \
                      acc[mi][ni] = __builtin_amdgcn_mfma_f32_16x16x32_bf16(      \
                          af[mi], bfr[ni], acc[mi][ni], 0, 0, 0);                 \
          } }

    ISSUE_A(0)
    ISSUE_B(0, 0)

    #pragma unroll
    for (int t8 = 0; t8 < 8; ++t8) {
        WRITE_A()                        // implicit wait on areg (old B stays in flight)
        if (t8 < 7) {
            ISSUE_A((t8 + 1) * 64)
            ISSUE_B((t8 + 1) * 64, (t8 + 1) & 1)
            // outstanding: B(t8)=2 oldest, A(t8+1)=8, B(t8+1)=2 -> retire only B(t8)
            asm volatile("s_waitcnt vmcnt(10) lgkmcnt(0)" ::: "memory");
        } else {
            asm volatile("s_waitcnt vmcnt(0) lgkmcnt(0)" ::: "memory");
        }
        BARRIER_FENCED()
        COMPUTE(t8 & 1)
        BARRIER_FENCED()
    }
    #undef ISSUE_A
    #undef ISSUE_B
    #undef WRITE_A
    #undef COMPUTE
    #undef BARRIER_FENCED

    // ---- per-class inverse norms (sumsq over fp32 W, reduced across k8 groups) ----
    #pragma unroll
    for (int jj = 0; jj < 4; ++jj) sSq[k8 * 128 + cg * 4 + jj] = ssq[jj];
    __syncthreads();
    if (t < 128) {
        float s = 0.f;
        #pragma unroll
        for (int gq = 0; gq < 8; ++gq) s += sSq[gq * 128 + t];
        sIwc[t] = rsqrtf(s);
    }
    __syncthreads();

    int   lb[4];
    float iwc[4][4];
    #pragma unroll
    for (int mi = 0; mi < 4; ++mi) {
        lb[mi] = wr * 64 + mi * 16 + kh * 4;
        #pragma unroll
        for (int r = 0; r < 4; ++r) iwc[mi][r] = sIwc[lb[mi] + r];
    }

    if (nb < 4) {
        // ---- logits + fused per-thread softmax/argmax over this block's classes ----
        #pragma unroll
        for (int ni = 0; ni < 2; ++ni) {
            int bl = wc * 32 + ni * 16 + r16;   // 0..63 within slice
            int b  = gn0 + bl;                  // batch row 0..255
            float xl  = xlen_a[b];
            float ixl = inv_xlen_a[b];
            float M = -INFINITY, S = 0.f, VM = -INFINITY; int VI = 0x7fffffff;
            #pragma unroll
            for (int mi = 0; mi < 4; ++mi) {
                int cb = m0 + lb[mi];
                f32x4 vout;
                #pragma unroll
                for (int r = 0; r < 4; ++r) {
                    float cosv = acc[mi][ni][r] * iwc[mi][r] * ixl;
                    cosv = fminf(1.f, fmaxf(-1.f, cosv));
                    float v = cosv * xl;
                    vout[r] = v;
                    if (cb + r < CLS_N) {
                        if (v > M) { S = S * __expf(M - v) + 1.f; M = v; }
                        else       { S += __expf(v - M); }
                        if (v > VM) { VM = v; VI = cb + r; }
                    }
                }
                if (cb + 3 < CLS_N) {
                    *reinterpret_cast<f32x4*>(&logits[(size_t)b * CLS_N + cb]) = vout;
                } else {
                    #pragma unroll
                    for (int r = 0; r < 4; ++r)
                        if (cb + r < CLS_N) logits[(size_t)b * CLS_N + cb + r] = vout[r];
                }
            }
            // merge across kh groups (lanes l, l^16, l^32, l^48)
            #pragma unroll
            for (int d = 16; d < 64; d <<= 1) {
                float m2  = __shfl_xor(M, d);
                float s2  = __shfl_xor(S, d);
                float vm2 = __shfl_xor(VM, d);
                int   vi2 = __shfl_xor(VI, d);
                merge4(M, S, VM, VI, m2, s2, vm2, vi2);
            }
            if (kh == 0) sPart[bl * 2 + wr] = make_float4(M, S, VM, __int_as_float(VI));
        }
        __syncthreads();
        if (t < 64) {
            float4 p0 = sPart[t * 2 + 0], p1 = sPart[t * 2 + 1];
            float M = p0.x, S = p0.y, VM = p0.z; int VI = __float_as_int(p0.w);
            merge4(M, S, VM, VI, p1.x, p1.y, p1.z, __float_as_int(p1.w));
            partials[(size_t)(gn0 + t) * NMB + m_blk] =
                make_float4(M, S, VM, __int_as_float(VI));
        }
    } else {
        // ---- MHE inter-class term ----
        float part = 0.f;
        #pragma unroll
        for (int ni = 0; ni < 2; ++ni) {
            int b = (gn0 - B_N) + wc * 32 + ni * 16 + r16;   // 0..255
            float iwy = inv_wny_a[b];
            int   yb  = y[b];
            #pragma unroll
            for (int mi = 0; mi < 4; ++mi) {
                int cb = m0 + lb[mi];
                #pragma unroll
                for (int r = 0; r < 4; ++r) {
                    int c = cb + r;
                    if (c < CLS_N && c != yb) {
                        float cww = acc[mi][ni][r] * iwc[mi][r] * iwy;
                        float d2 = fmaxf(2.f - 2.f * cww, 0.f);
                        part += 1.f / d2;
                    }
                }
            }
        }
        red[t] = part;
        __syncthreads();
        for (int s = 128; s > 0; s >>= 1) {
            if (t < s) red[t] += red[t + s];
            __syncthreads();
        }
        if (t == 0) atomicAdd(inter_sum, red[0]);
    }
}

// ---------------- reduce: merge NMB partials per batch row, CE fixup + argmax ----------------
__global__ __launch_bounds__(64) void reduce_kernel(
    const float4* __restrict__ partials, const float* __restrict__ logits,
    const int* __restrict__ y, const float* __restrict__ mod_val_a,
    float* __restrict__ ce_sum, float* __restrict__ acc_sum)
{
    const int b = blockIdx.x;
    const int t = threadIdx.x;
    float M = -INFINITY, S = 0.f, VM = -INFINITY; int VI = 0x7fffffff;
    for (int i = t; i < NMB; i += 64) {
        float4 p = partials[(size_t)b * NMB + i];
        merge4(M, S, VM, VI, p.x, p.y, p.z, __float_as_int(p.w));
    }
    #pragma unroll
    for (int d = 1; d < 64; d <<= 1) {
        float m2  = __shfl_xor(M, d);
        float s2  = __shfl_xor(S, d);
        float vm2 = __shfl_xor(VM, d);
        int   vi2 = __shfl_xor(VI, d);
        merge4(M, S, VM, VI, m2, s2, vm2, vi2);
    }
    if (t == 0) {
        int   yb  = y[b];
        float vyb = logits[(size_t)b * CLS_N + yb];
        float mv  = mod_val_a[b];
        float m2 = fmaxf(M, mv);
        float s2 = S * __expf(M - m2) - __expf(vyb - m2) + __expf(mv - m2);
        float lse = m2 + logf(s2);
        atomicAdd(ce_sum, -(mv - lse));
        if (VI == yb) atomicAdd(acc_sum, 1.f);
    }
}

__global__ void finalize_kernel(const float* __restrict__ accums, float* __restrict__ out)
{
    float ce    = accums[0] / (float)B_N;
    float acc   = accums[1] / (float)B_N;
    float inter = accums[2] / (float)((double)B_N * (CLS_N - 1));
    out[0] = ce + 0.01f * inter;
    out[(size_t)1 + (size_t)B_N * CLS_N + 0] = acc;
    out[(size_t)1 + (size_t)B_N * CLS_N + 1] = inter;
}

extern "C" void kernel_launch(void* const* d_in, const int* in_sizes, int n_in,
                              void* d_out, int out_size, void* d_ws, size_t ws_size,
                              hipStream_t stream) {
    const float* emb = (const float*)d_in[0];
    const int*   y   = (const int*)d_in[1];
    const float* W   = (const float*)d_in[2];
    float* out = (float*)d_out;
    float* logits = out + 1;   // [loss, logits(256x20000), acc, inter]

    // ws layout (bytes)
    const size_t ABF_OFF  = 0;                                  // 512*512*2 = 524288
    const size_t PART_OFF = 524288;                             // 256*157*16
    const size_t SC_OFF   = PART_OFF + (size_t)B_N * NMB * 16;

    unsigned short* Abf = (unsigned short*)((char*)d_ws + ABF_OFF);
    float4* partials   = (float4*)((char*)d_ws + PART_OFF);
    float*  xlen_a     = (float*)((char*)d_ws + SC_OFF);
    float*  inv_xlen_a = xlen_a + 256;
    float*  inv_wny_a  = xlen_a + 512;
    float*  mod_val_a  = xlen_a + 768;
    float*  accums     = xlen_a + 1024;

    hipMemsetAsync(accums, 0, 3 * sizeof(float), stream);

    prep_kernel<<<B_N, 256, 0, stream>>>(emb, y, W, Abf,
                                         xlen_a, inv_xlen_a, inv_wny_a, mod_val_a);
    mfma_gemm_kernel<<<NMB * 8, 256, 0, stream>>>(W, Abf, y,
                                                  xlen_a, inv_xlen_a, inv_wny_a,
                                                  logits, partials, accums + 2);
    reduce_kernel<<<B_N, 64, 0, stream>>>(partials, logits, y, mod_val_a,
                                          accums + 0, accums + 1);
    finalize_kernel<<<1, 1, 0, stream>>>(accums, out);
}

// Round 8
// 74.177 us; speedup vs baseline: 1.1480x; 1.1480x over previous
//
#include <hip/hip_runtime.h>
#include <hip/hip_bf16.h>
#include <math.h>

#define B_N   256
#define EMB_N 512
#define CLS_N 20000
#define NMB   313          // class tiles of 64 (313*64 = 20032 >= 20000)
#define PI_F  3.14159265f
#define F_CONST ((float)(1.1 / 1501.1))

typedef __bf16 bf16x8 __attribute__((ext_vector_type(8)));
typedef float  f32x4  __attribute__((ext_vector_type(4)));
typedef unsigned short u16x8 __attribute__((ext_vector_type(8)));

__device__ __forceinline__ unsigned short f2bf(float f) {
    unsigned u = __float_as_uint(f);
    unsigned r = (u + 0x7FFFu + ((u >> 16) & 1u)) >> 16;  // RNE
    return (unsigned short)r;
}

__device__ __forceinline__ void merge4(float& M, float& S, float& VM, int& VI,
                                       float m2, float s2, float vm2, int vi2) {
    float mn = fmaxf(M, m2);
    if (mn == -INFINITY) { S = 0.f; }
    else S = S * __expf(M - mn) + s2 * __expf(m2 - mn);
    M = mn;
    if (vm2 > VM || (vm2 == VM && vi2 < VI)) { VM = vm2; VI = vi2; }
}

// ---------------- prep: per-row scalars + bf16 stacked batch operand ----------------
__global__ __launch_bounds__(256) void prep_kernel(
    const float* __restrict__ emb, const int* __restrict__ y,
    const float* __restrict__ W,
    unsigned short* __restrict__ Abf,
    float* __restrict__ xlen_a, float* __restrict__ inv_xlen_a,
    float* __restrict__ inv_wny_a, float* __restrict__ mod_val_a)
{
    const int b = blockIdx.x;
    const int t = threadIdx.x;
    const int yb = y[b];
    const float* erow = emb + (size_t)b * EMB_N;
    float se = 0.f, sw = 0.f, dt = 0.f;
    for (int e = t; e < EMB_N; e += 256) {
        float ev = erow[e];
        float wv = W[(size_t)e * CLS_N + yb];
        Abf[(size_t)b * EMB_N + e]         = f2bf(ev);
        Abf[(size_t)(B_N + b) * EMB_N + e] = f2bf(wv);
        se += ev * ev; sw += wv * wv; dt += ev * wv;
    }
    __shared__ float r0[256], r1[256], r2[256];
    r0[t] = se; r1[t] = sw; r2[t] = dt;
    __syncthreads();
    for (int s = 128; s > 0; s >>= 1) {
        if (t < s) { r0[t] += r0[t + s]; r1[t] += r1[t + s]; r2[t] += r2[t + s]; }
        __syncthreads();
    }
    if (t == 0) {
        float xlen = sqrtf(r0[0]);
        float wn   = sqrtf(r1[0]);
        float inv_x = 1.f / xlen;
        float inv_w = 1.f / wn;
        float cos_t = r2[0] * inv_w * inv_x;
        cos_t = fminf(1.f, fmaxf(-1.f, cos_t));
        float c2 = cos_t * cos_t;
        float cos_m = 8.f * c2 * c2 - 8.f * c2 + 1.f;
        float theta = acosf(cos_t);
        float k = floorf(4.f * theta / PI_F);
        float sgn = 1.f - 2.f * fmodf(k, 2.f);
        float phi = sgn * cos_m - 2.f * k;
        float cos_s = cos_t * xlen;
        float phi_s = phi * xlen;
        xlen_a[b] = xlen;
        inv_xlen_a[b] = inv_x;
        inv_wny_a[b] = inv_w;
        mod_val_a[b] = cos_s + F_CONST * (phi_s - cos_s);
    }
}

// ---------------- fused MFMA GEMM ----------------
// Tile: 64 classes x 128 batch. 1252 blocks (313 tiles x 4 batch-slices), all co-resident.
// A: W fp32 -> reg -> bf16 LDS (dbuf, 80B padded rows). B: register-direct from L2 (dbuf).
// BK=32, 16 steps, one fenced s_barrier + lgkmcnt(0) per step; vmcnt never drained in-loop.
__global__ __launch_bounds__(256, 4) void mfma_gemm_kernel(
    const float* __restrict__ W, const unsigned short* __restrict__ Abf,
    const int* __restrict__ y,
    const float* __restrict__ xlen_a, const float* __restrict__ inv_xlen_a,
    const float* __restrict__ inv_wny_a,
    float* __restrict__ logits, float4* __restrict__ partials,
    float* __restrict__ inter_sum)
{
    __shared__ alignas(16) char smem[2][5120];   // A dbuf: 64 rows x 80B
    // epilogue overlays (A buffers dead after the loop)
    float*  sSq   = (float*)smem;                 // 256 floats
    float*  sIwc  = (float*)((char*)smem + 1024); // 64 floats
    float4* sPart = (float4*)((char*)smem + 1280);// 128*2 = 4KB
    float*  red   = (float*)((char*)smem + 5376); // 256 floats

    // bijective XCD-chunked mapping: 1252 = 4*157 + 4*156
    const int bid = blockIdx.x;
    const int xcd = bid & 7;
    const int idx = bid >> 3;
    const int g   = (xcd < 4 ? xcd * 157 : 4 * 157 + (xcd - 4) * 156) + idx;
    const int tile  = g >> 2;
    const int slice = g & 3;            // 0,1: logits (emb rows); 2,3: MHE (Wg rows)
    const int m0    = tile * 64;
    const int gn0   = slice * 128;      // stacked-batch base

    const int t    = threadIdx.x;
    const int lane = t & 63;
    const int wid  = t >> 6;
    const int wr   = wid >> 1;          // class half (32 rows)
    const int wcb  = wid & 1;           // batch half (64 cols)
    const int r16  = lane & 15;
    const int kh   = lane >> 4;

    // A staging map: thread = class (lane), k-octet (wid)
    const int cls = (m0 + lane < CLS_N) ? (m0 + lane) : (CLS_N - 1);

    f32x4 acc[2][4] = {};
    float aq[2][8];
    bf16x8 bq[2][4];
    float ssq = 0.f;

    #define ISSUE_A(w)                                                            \
        { _Pragma("unroll")                                                       \
          for (int p = 0; p < 8; ++p)                                             \
              aq[(w) & 1][p] = W[(size_t)((w) * 32 + wid * 8 + p) * CLS_N + cls]; \
        }

    #define ISSUE_B(w)                                                            \
        { _Pragma("unroll")                                                       \
          for (int ni = 0; ni < 4; ++ni) {                                        \
              int row = gn0 + wcb * 64 + ni * 16 + r16;                           \
              bq[(w) & 1][ni] = *reinterpret_cast<const bf16x8*>(                 \
                  Abf + (size_t)row * EMB_N + (w) * 32 + kh * 8);                 \
          } }

    #define WRITE_A(w)                                                            \
        { u16x8 u; float sq = 0.f;                                                \
          _Pragma("unroll")                                                       \
          for (int p = 0; p < 8; ++p) {                                           \
              float v = aq[(w) & 1][p];                                           \
              u[p] = f2bf(v); sq += v * v;                                        \
          }                                                                       \
          ssq += sq;                                                              \
          *reinterpret_cast<u16x8*>(&smem[(w) & 1][lane * 80 + wid * 16]) = u; }

    #define COMPUTE(tt)                                                           \
        { bf16x8 af[2];                                                           \
          _Pragma("unroll")                                                       \
          for (int mi = 0; mi < 2; ++mi)                                          \
              af[mi] = *reinterpret_cast<const bf16x8*>(                          \
                  &smem[(tt) & 1][(wr * 32 + mi * 16 + r16) * 80 + kh * 16]);     \
          _Pragma("unroll")                                                       \
          for (int mi = 0; mi < 2; ++mi)                                          \
              _Pragma("unroll")                                                   \
              for (int ni = 0; ni < 4; ++ni)                                      \
                  acc[mi][ni] = __builtin_amdgcn_mfma_f32_16x16x32_bf16(          \
                      af[mi], bq[(tt) & 1][ni], acc[mi][ni], 0, 0, 0); }

    #define STEP_BARRIER()                                         \
        { __builtin_amdgcn_sched_barrier(0);                       \
          asm volatile("s_waitcnt lgkmcnt(0)" ::: "memory");       \
          __builtin_amdgcn_sched_barrier(0);                       \
          asm volatile("s_barrier" ::: "memory");                  \
          __builtin_amdgcn_sched_barrier(0); }

    ISSUE_A(0) ISSUE_B(0)
    WRITE_A(0)            // auto-waits aq[0] loads; vmcnt for B stays pending
    ISSUE_A(1) ISSUE_B(1)
    STEP_BARRIER()

    #pragma unroll
    for (int tt = 0; tt < 16; ++tt) {
        COMPUTE(tt)                       // auto vmcnt-wait on bq[tt&1] only
        if (tt < 15) {
            WRITE_A(tt + 1)               // writes idle buffer; safe pre-barrier
            if (tt < 14) { ISSUE_A(tt + 2) ISSUE_B(tt + 2) }
            STEP_BARRIER()
        }
    }
    #undef ISSUE_A
    #undef ISSUE_B
    #undef WRITE_A
    #undef COMPUTE
    #undef STEP_BARRIER

    __syncthreads();   // full drain; A buffers become epilogue overlays

    // ---- per-class inverse norms ----
    sSq[wid * 64 + lane] = ssq;
    __syncthreads();
    if (t < 64) {
        float s = sSq[t] + sSq[64 + t] + sSq[128 + t] + sSq[192 + t];
        sIwc[t] = rsqrtf(s);
    }
    __syncthreads();

    float iwc[2][4];
    #pragma unroll
    for (int mi = 0; mi < 2; ++mi)
        #pragma unroll
        for (int r = 0; r < 4; ++r)
            iwc[mi][r] = sIwc[wr * 32 + mi * 16 + kh * 4 + r];

    if (slice < 2) {
        // ---- logits + fused per-thread softmax/argmax ----
        #pragma unroll
        for (int ni = 0; ni < 4; ++ni) {
            int bl = wcb * 64 + ni * 16 + r16;   // 0..127
            int b  = gn0 + bl;                   // 0..255
            float xl  = xlen_a[b];
            float ixl = inv_xlen_a[b];
            float M = -INFINITY, S = 0.f, VM = -INFINITY; int VI = 0x7fffffff;
            #pragma unroll
            for (int mi = 0; mi < 2; ++mi) {
                int cb = m0 + wr * 32 + mi * 16 + kh * 4;
                if (cb < CLS_N) {            // quad fully valid or fully invalid
                    f32x4 vout;
                    #pragma unroll
                    for (int r = 0; r < 4; ++r) {
                        float cosv = acc[mi][ni][r] * iwc[mi][r] * ixl;
                        cosv = fminf(1.f, fmaxf(-1.f, cosv));
                        float v = cosv * xl;
                        vout[r] = v;
                        if (v > M) { S = S * __expf(M - v) + 1.f; M = v; }
                        else       { S += __expf(v - M); }
                        if (v > VM) { VM = v; VI = cb + r; }
                    }
                    *reinterpret_cast<f32x4*>(&logits[(size_t)b * CLS_N + cb]) = vout;
                }
            }
            #pragma unroll
            for (int d = 16; d < 64; d <<= 1) {
                float m2  = __shfl_xor(M, d);
                float s2  = __shfl_xor(S, d);
                float vm2 = __shfl_xor(VM, d);
                int   vi2 = __shfl_xor(VI, d);
                merge4(M, S, VM, VI, m2, s2, vm2, vi2);
            }
            if (kh == 0) sPart[bl * 2 + wr] = make_float4(M, S, VM, __int_as_float(VI));
        }
        __syncthreads();
        if (t < 128) {
            float4 p0 = sPart[t * 2 + 0], p1 = sPart[t * 2 + 1];
            float M = p0.x, S = p0.y, VM = p0.z; int VI = __float_as_int(p0.w);
            merge4(M, S, VM, VI, p1.x, p1.y, p1.z, __float_as_int(p1.w));
            partials[(size_t)(gn0 + t) * NMB + tile] =
                make_float4(M, S, VM, __int_as_float(VI));
        }
    } else {
        // ---- MHE inter-class term ----
        float part = 0.f;
        #pragma unroll
        for (int ni = 0; ni < 4; ++ni) {
            int b = (slice - 2) * 128 + wcb * 64 + ni * 16 + r16;   // 0..255
            float iwy = inv_wny_a[b];
            int   yb  = y[b];
            #pragma unroll
            for (int mi = 0; mi < 2; ++mi) {
                int cb = m0 + wr * 32 + mi * 16 + kh * 4;
                #pragma unroll
                for (int r = 0; r < 4; ++r) {
                    int c = cb + r;
                    if (c < CLS_N && c != yb) {
                        float cww = acc[mi][ni][r] * iwc[mi][r] * iwy;
                        float d2 = fmaxf(2.f - 2.f * cww, 0.f);
                        part += 1.f / d2;
                    }
                }
            }
        }
        red[t] = part;
        __syncthreads();
        for (int s = 128; s > 0; s >>= 1) {
            if (t < s) red[t] += red[t + s];
            __syncthreads();
        }
        if (t == 0) atomicAdd(inter_sum, red[0]);
    }
}

// ---------------- reduce: merge NMB partials per batch row, CE fixup + argmax ----------------
__global__ __launch_bounds__(64) void reduce_kernel(
    const float4* __restrict__ partials, const float* __restrict__ logits,
    const int* __restrict__ y, const float* __restrict__ mod_val_a,
    float* __restrict__ ce_sum, float* __restrict__ acc_sum)
{
    const int b = blockIdx.x;
    const int t = threadIdx.x;
    float M = -INFINITY, S = 0.f, VM = -INFINITY; int VI = 0x7fffffff;
    for (int i = t; i < NMB; i += 64) {
        float4 p = partials[(size_t)b * NMB + i];
        merge4(M, S, VM, VI, p.x, p.y, p.z, __float_as_int(p.w));
    }
    #pragma unroll
    for (int d = 1; d < 64; d <<= 1) {
        float m2  = __shfl_xor(M, d);
        float s2  = __shfl_xor(S, d);
        float vm2 = __shfl_xor(VM, d);
        int   vi2 = __shfl_xor(VI, d);
        merge4(M, S, VM, VI, m2, s2, vm2, vi2);
    }
    if (t == 0) {
        int   yb  = y[b];
        float vyb = logits[(size_t)b * CLS_N + yb];
        float mv  = mod_val_a[b];
        float m2 = fmaxf(M, mv);
        float s2 = S * __expf(M - m2) - __expf(vyb - m2) + __expf(mv - m2);
        float lse = m2 + logf(s2);
        atomicAdd(ce_sum, -(mv - lse));
        if (VI == yb) atomicAdd(acc_sum, 1.f);
    }
}

__global__ void finalize_kernel(const float* __restrict__ accums, float* __restrict__ out)
{
    float ce    = accums[0] / (float)B_N;
    float acc   = accums[1] / (float)B_N;
    float inter = accums[2] / (float)((double)B_N * (CLS_N - 1));
    out[0] = ce + 0.01f * inter;
    out[(size_t)1 + (size_t)B_N * CLS_N + 0] = acc;
    out[(size_t)1 + (size_t)B_N * CLS_N + 1] = inter;
}

extern "C" void kernel_launch(void* const* d_in, const int* in_sizes, int n_in,
                              void* d_out, int out_size, void* d_ws, size_t ws_size,
                              hipStream_t stream) {
    const float* emb = (const float*)d_in[0];
    const int*   y   = (const int*)d_in[1];
    const float* W   = (const float*)d_in[2];
    float* out = (float*)d_out;
    float* logits = out + 1;   // [loss, logits(256x20000), acc, inter]

    // ws layout (bytes)
    const size_t ABF_OFF  = 0;                                  // 512*512*2 = 524288
    const size_t PART_OFF = 524288;                             // 256*313*16
    const size_t SC_OFF   = PART_OFF + (size_t)B_N * NMB * 16;

    unsigned short* Abf = (unsigned short*)((char*)d_ws + ABF_OFF);
    float4* partials   = (float4*)((char*)d_ws + PART_OFF);
    float*  xlen_a     = (float*)((char*)d_ws + SC_OFF);
    float*  inv_xlen_a = xlen_a + 256;
    float*  inv_wny_a  = xlen_a + 512;
    float*  mod_val_a  = xlen_a + 768;
    float*  accums     = xlen_a + 1024;

    hipMemsetAsync(accums, 0, 3 * sizeof(float), stream);

    prep_kernel<<<B_N, 256, 0, stream>>>(emb, y, W, Abf,
                                         xlen_a, inv_xlen_a, inv_wny_a, mod_val_a);
    mfma_gemm_kernel<<<1252, 256, 0, stream>>>(W, Abf, y,
                                               xlen_a, inv_xlen_a, inv_wny_a,
                                               logits, partials, accums + 2);
    reduce_kernel<<<B_N, 64, 0, stream>>>(partials, logits, y, mod_val_a,
                                          accums + 0, accums + 1);
    finalize_kernel<<<1, 1, 0, stream>>>(accums, out);
}

// Round 9
// 55.926 us; speedup vs baseline: 1.5227x; 1.3264x over previous
//
#include <hip/hip_runtime.h>
#include <hip/hip_bf16.h>
#include <math.h>

#define B_N   256
#define EMB_N 512
#define CLS_N 20000
#define NMB   157          // class tiles of 128 (157*128 = 20096 >= 20000)
#define PI_F  3.14159265f
#define F_CONST ((float)(1.1 / 1501.1))

typedef __bf16 bf16x8 __attribute__((ext_vector_type(8)));
typedef float  f32x4  __attribute__((ext_vector_type(4)));
typedef unsigned short u16x8 __attribute__((ext_vector_type(8)));

__device__ __forceinline__ unsigned short f2bf(float f) {
    unsigned u = __float_as_uint(f);
    unsigned r = (u + 0x7FFFu + ((u >> 16) & 1u)) >> 16;  // RNE
    return (unsigned short)r;
}

__device__ __forceinline__ void merge4(float& M, float& S, float& VM, int& VI,
                                       float m2, float s2, float vm2, int vi2) {
    float mn = fmaxf(M, m2);
    if (mn == -INFINITY) { S = 0.f; }
    else S = S * __expf(M - mn) + s2 * __expf(m2 - mn);
    M = mn;
    if (vm2 > VM || (vm2 == VM && vi2 < VI)) { VM = vm2; VI = vi2; }
}

// ---------------- prep: per-row scalars + bf16 stacked batch operand ----------------
__global__ __launch_bounds__(256) void prep_kernel(
    const float* __restrict__ emb, const int* __restrict__ y,
    const float* __restrict__ W,
    unsigned short* __restrict__ Abf,
    float* __restrict__ xlen_a, float* __restrict__ inv_xlen_a,
    float* __restrict__ inv_wny_a, float* __restrict__ mod_val_a)
{
    const int b = blockIdx.x;
    const int t = threadIdx.x;
    const int yb = y[b];
    const float* erow = emb + (size_t)b * EMB_N;
    float se = 0.f, sw = 0.f, dt = 0.f;
    for (int e = t; e < EMB_N; e += 256) {
        float ev = erow[e];
        float wv = W[(size_t)e * CLS_N + yb];
        Abf[(size_t)b * EMB_N + e]         = f2bf(ev);
        Abf[(size_t)(B_N + b) * EMB_N + e] = f2bf(wv);
        se += ev * ev; sw += wv * wv; dt += ev * wv;
    }
    __shared__ float r0[256], r1[256], r2[256];
    r0[t] = se; r1[t] = sw; r2[t] = dt;
    __syncthreads();
    for (int s = 128; s > 0; s >>= 1) {
        if (t < s) { r0[t] += r0[t + s]; r1[t] += r1[t + s]; r2[t] += r2[t + s]; }
        __syncthreads();
    }
    if (t == 0) {
        float xlen = sqrtf(r0[0]);
        float wn   = sqrtf(r1[0]);
        float inv_x = 1.f / xlen;
        float inv_w = 1.f / wn;
        float cos_t = r2[0] * inv_w * inv_x;
        cos_t = fminf(1.f, fmaxf(-1.f, cos_t));
        float c2 = cos_t * cos_t;
        float cos_m = 8.f * c2 * c2 - 8.f * c2 + 1.f;
        float theta = acosf(cos_t);
        float k = floorf(4.f * theta / PI_F);
        float sgn = 1.f - 2.f * fmodf(k, 2.f);
        float phi = sgn * cos_m - 2.f * k;
        float cos_s = cos_t * xlen;
        float phi_s = phi * xlen;
        xlen_a[b] = xlen;
        inv_xlen_a[b] = inv_x;
        inv_wny_a[b] = inv_w;
        mod_val_a[b] = cos_s + F_CONST * (phi_s - cos_s);
    }
}

// ---------------- fused MFMA GEMM ----------------
// Tile: 128 classes x 128 batch; 628 blocks = 157 tiles x 4 slices, m204 XCD-bijective
// swizzle keeps a tile's 4 slices on one XCD (W L2-shared). A: W fp32 -> reg (f32x2
// class-pairs, coalesced) -> bf16 LDS (80B rows), in-kernel sumsq. B: global_load_lds
// with read-side XOR swizzle via pre-swizzled source. BK=32, 16 steps, counted vmcnt(10).
__global__ __launch_bounds__(256, 3) void mfma_gemm_kernel(
    const float* __restrict__ W, const unsigned short* __restrict__ Abf,
    const int* __restrict__ y,
    const float* __restrict__ xlen_a, const float* __restrict__ inv_xlen_a,
    const float* __restrict__ inv_wny_a,
    float* __restrict__ logits, float4* __restrict__ partials,
    float* __restrict__ inter_sum)
{
    __shared__ alignas(16) char sA[2][10240];   // 128 class rows x 80B (64B data + 16 pad)
    __shared__ alignas(16) char sB[2][8192];    // 128 batch rows x 64B, dbuf
    // epilogue overlays (sA dead after loop)
    float*  sSq   = (float*)sA;                   // [4][128] = 2 KB
    float*  sIwc  = (float*)((char*)sA + 2048);   // 128 floats
    float4* sPart = (float4*)((char*)sA + 2560);  // [128][2] = 4 KB
    float*  red   = (float*)((char*)sA + 6656);   // 256 floats

    // m204 bijective XCD-chunked mapping: 628 = 4*79 + 4*78
    const int orig = blockIdx.x;
    const int xcd  = orig & 7;
    const int wgid = (xcd < 4 ? xcd * 79 : 316 + (xcd - 4) * 78) + (orig >> 3);
    const int tile  = wgid >> 2;
    const int slice = wgid & 3;          // 0,1: logits; 2,3: MHE
    const int m0    = tile * 128;
    const int gn0   = slice * 128;

    const int t    = threadIdx.x;
    const int lane = t & 63;
    const int wid  = t >> 6;
    const int wr   = wid >> 1;           // class half (64 rows)
    const int wc   = wid & 1;            // batch half (64 cols)
    const int r16  = lane & 15;
    const int kh   = lane >> 4;

    const char* Bb = (const char*)Abf;

    f32x4 acc[4][4] = {};
    float2 aq[2][8];
    float ssq0 = 0.f, ssq1 = 0.f;

    // A staging: thread = class pair (c2, c2+1), k-octet ko
    const int c2 = (t & 63) * 2;
    const int ko = t >> 6;
    const int gc = min(m0 + c2, CLS_N - 2);

    #define ISSUE_A(kt, s)                                                        \
        { _Pragma("unroll")                                                       \
          for (int p = 0; p < 8; ++p)                                             \
              aq[s][p] = *reinterpret_cast<const float2*>(                        \
                  &W[(size_t)((kt) + ko * 8 + p) * CLS_N + gc]);                  \
        }

    #define ISSUE_B(kt, buf)                                                      \
        { _Pragma("unroll")                                                       \
          for (int i = 0; i < 2; ++i) {                                           \
              int slot = wid * 2 + i;                                             \
              int row  = slot * 16 + (lane >> 2);                                 \
              int srcq = (lane & 3) ^ ((lane >> 2) & 3);                          \
              __builtin_amdgcn_global_load_lds(                                   \
                  (const __attribute__((address_space(1))) unsigned int*)         \
                      (Bb + (size_t)(gn0 + row) * 1024 + (size_t)(kt) * 2         \
                          + srcq * 16),                                           \
                  (__attribute__((address_space(3))) unsigned int*)               \
                      (sB[buf] + slot * 1024),                                    \
                  16, 0, 0);                                                      \
          } }

    #define WRITE_A(s, buf)                                                       \
        { u16x8 u0, u1; float s0 = 0.f, s1 = 0.f;                                 \
          _Pragma("unroll")                                                       \
          for (int p = 0; p < 8; ++p) {                                           \
              float vx = aq[s][p].x, vy = aq[s][p].y;                             \
              u0[p] = f2bf(vx); u1[p] = f2bf(vy);                                 \
              s0 += vx * vx; s1 += vy * vy;                                       \
          }                                                                       \
          ssq0 += s0; ssq1 += s1;                                                 \
          *reinterpret_cast<u16x8*>(&sA[buf][c2 * 80 + ko * 16]) = u0;            \
          *reinterpret_cast<u16x8*>(&sA[buf][(c2 + 1) * 80 + ko * 16]) = u1; }

    #define COMPUTE(buf)                                                          \
        { bf16x8 af[4], bfr[4];                                                   \
          _Pragma("unroll")                                                       \
          for (int mi = 0; mi < 4; ++mi) {                                        \
              int row = wr * 64 + mi * 16 + r16;                                  \
              af[mi] = *reinterpret_cast<const bf16x8*>(                          \
                  &sA[buf][row * 80 + kh * 16]);                                  \
          }                                                                       \
          _Pragma("unroll")                                                       \
          for (int ni = 0; ni < 4; ++ni) {                                        \
              int rowb = wc * 64 + ni * 16 + r16;                                 \
              bfr[ni] = *reinterpret_cast<const bf16x8*>(                         \
                  &sB[buf][rowb * 64 + ((kh ^ (rowb & 3)) * 16)]);                \
          }                                                                       \
          _Pragma("unroll")                                                       \
          for (int mi = 0; mi < 4; ++mi)                                          \
              _Pragma("unroll")                                                   \
              for (int ni = 0; ni < 4; ++ni)                                      \
                  acc[mi][ni] = __builtin_amdgcn_mfma_f32_16x16x32_bf16(          \
                      af[mi], bfr[ni], acc[mi][ni], 0, 0, 0); }

    #define FENCE() __builtin_amdgcn_sched_barrier(0);

    ISSUE_A(0, 0)
    ISSUE_B(0, 0)

    #pragma unroll
    for (int tt = 0; tt < 16; ++tt) {
        if (tt < 15) {
            ISSUE_A((tt + 1) * 32, (tt + 1) & 1)
            ISSUE_B((tt + 1) * 32, (tt + 1) & 1)
            WRITE_A(tt & 1, tt & 1)     // implicit vmcnt(12): waits A(tt) only
            FENCE()
            asm volatile("s_waitcnt vmcnt(10) lgkmcnt(0)" ::: "memory"); // B(tt) done, 10 in flight
        } else {
            WRITE_A(tt & 1, tt & 1)
            FENCE()
            asm volatile("s_waitcnt vmcnt(0) lgkmcnt(0)" ::: "memory");
        }
        FENCE()
        asm volatile("s_barrier" ::: "memory");
        FENCE()
        COMPUTE(tt & 1)
        FENCE()
        asm volatile("s_barrier" ::: "memory");
        FENCE()
    }
    #undef ISSUE_A
    #undef ISSUE_B
    #undef WRITE_A
    #undef COMPUTE
    #undef FENCE

    __syncthreads();   // drain; sA becomes epilogue overlay

    // ---- per-class inverse norms (4 k-octet partials per class) ----
    sSq[ko * 128 + c2]     = ssq0;
    sSq[ko * 128 + c2 + 1] = ssq1;
    __syncthreads();
    if (t < 128) {
        float s = sSq[t] + sSq[128 + t] + sSq[256 + t] + sSq[384 + t];
        sIwc[t] = rsqrtf(s);
    }
    __syncthreads();

    float iwc[4][4];
    #pragma unroll
    for (int mi = 0; mi < 4; ++mi)
        #pragma unroll
        for (int r = 0; r < 4; ++r)
            iwc[mi][r] = sIwc[wr * 64 + mi * 16 + kh * 4 + r];

    if (slice < 2) {
        // ---- logits + fused per-thread softmax/argmax ----
        #pragma unroll
        for (int ni = 0; ni < 4; ++ni) {
            int bl = wc * 64 + ni * 16 + r16;   // 0..127
            int b  = gn0 + bl;                   // 0..255
            float xl  = xlen_a[b];
            float ixl = inv_xlen_a[b];
            float M = -INFINITY, S = 0.f, VM = -INFINITY; int VI = 0x7fffffff;
            #pragma unroll
            for (int mi = 0; mi < 4; ++mi) {
                int cb = m0 + wr * 64 + mi * 16 + kh * 4;
                if (cb < CLS_N) {            // quad-aligned boundary: fully valid
                    f32x4 vout;
                    #pragma unroll
                    for (int r = 0; r < 4; ++r) {
                        float cosv = acc[mi][ni][r] * iwc[mi][r] * ixl;
                        cosv = fminf(1.f, fmaxf(-1.f, cosv));
                        float v = cosv * xl;
                        vout[r] = v;
                        if (v > M) { S = S * __expf(M - v) + 1.f; M = v; }
                        else       { S += __expf(v - M); }
                        if (v > VM) { VM = v; VI = cb + r; }
                    }
                    *reinterpret_cast<f32x4*>(&logits[(size_t)b * CLS_N + cb]) = vout;
                }
            }
            #pragma unroll
            for (int d = 16; d < 64; d <<= 1) {
                float m2  = __shfl_xor(M, d);
                float s2  = __shfl_xor(S, d);
                float vm2 = __shfl_xor(VM, d);
                int   vi2 = __shfl_xor(VI, d);
                merge4(M, S, VM, VI, m2, s2, vm2, vi2);
            }
            if (kh == 0) sPart[bl * 2 + wr] = make_float4(M, S, VM, __int_as_float(VI));
        }
        __syncthreads();
        if (t < 128) {
            float4 p0 = sPart[t * 2 + 0], p1 = sPart[t * 2 + 1];
            float M = p0.x, S = p0.y, VM = p0.z; int VI = __float_as_int(p0.w);
            merge4(M, S, VM, VI, p1.x, p1.y, p1.z, __float_as_int(p1.w));
            partials[(size_t)(gn0 + t) * NMB + tile] =
                make_float4(M, S, VM, __int_as_float(VI));
        }
    } else {
        // ---- MHE inter-class term ----
        float part = 0.f;
        #pragma unroll
        for (int ni = 0; ni < 4; ++ni) {
            int b = (slice - 2) * 128 + wc * 64 + ni * 16 + r16;   // 0..255
            float iwy = inv_wny_a[b];
            int   yb  = y[b];
            #pragma unroll
            for (int mi = 0; mi < 4; ++mi) {
                int cb = m0 + wr * 64 + mi * 16 + kh * 4;
                #pragma unroll
                for (int r = 0; r < 4; ++r) {
                    int c = cb + r;
                    if (c < CLS_N && c != yb) {
                        float cww = acc[mi][ni][r] * iwc[mi][r] * iwy;
                        float d2 = fmaxf(2.f - 2.f * cww, 0.f);
                        part += 1.f / d2;
                    }
                }
            }
        }
        red[t] = part;
        __syncthreads();
        for (int s = 128; s > 0; s >>= 1) {
            if (t < s) red[t] += red[t + s];
            __syncthreads();
        }
        if (t == 0) atomicAdd(inter_sum, red[0]);
    }
}

// ---------------- reduce: merge NMB partials per batch row, CE fixup + argmax ----------------
__global__ __launch_bounds__(64) void reduce_kernel(
    const float4* __restrict__ partials, const float* __restrict__ logits,
    const int* __restrict__ y, const float* __restrict__ mod_val_a,
    float* __restrict__ ce_sum, float* __restrict__ acc_sum)
{
    const int b = blockIdx.x;
    const int t = threadIdx.x;
    float M = -INFINITY, S = 0.f, VM = -INFINITY; int VI = 0x7fffffff;
    for (int i = t; i < NMB; i += 64) {
        float4 p = partials[(size_t)b * NMB + i];
        merge4(M, S, VM, VI, p.x, p.y, p.z, __float_as_int(p.w));
    }
    #pragma unroll
    for (int d = 1; d < 64; d <<= 1) {
        float m2  = __shfl_xor(M, d);
        float s2  = __shfl_xor(S, d);
        float vm2 = __shfl_xor(VM, d);
        int   vi2 = __shfl_xor(VI, d);
        merge4(M, S, VM, VI, m2, s2, vm2, vi2);
    }
    if (t == 0) {
        int   yb  = y[b];
        float vyb = logits[(size_t)b * CLS_N + yb];
        float mv  = mod_val_a[b];
        float m2 = fmaxf(M, mv);
        float s2 = S * __expf(M - m2) - __expf(vyb - m2) + __expf(mv - m2);
        float lse = m2 + logf(s2);
        atomicAdd(ce_sum, -(mv - lse));
        if (VI == yb) atomicAdd(acc_sum, 1.f);
    }
}

__global__ void finalize_kernel(const float* __restrict__ accums, float* __restrict__ out)
{
    float ce    = accums[0] / (float)B_N;
    float acc   = accums[1] / (float)B_N;
    float inter = accums[2] / (float)((double)B_N * (CLS_N - 1));
    out[0] = ce + 0.01f * inter;
    out[(size_t)1 + (size_t)B_N * CLS_N + 0] = acc;
    out[(size_t)1 + (size_t)B_N * CLS_N + 1] = inter;
}

extern "C" void kernel_launch(void* const* d_in, const int* in_sizes, int n_in,
                              void* d_out, int out_size, void* d_ws, size_t ws_size,
                              hipStream_t stream) {
    const float* emb = (const float*)d_in[0];
    const int*   y   = (const int*)d_in[1];
    const float* W   = (const float*)d_in[2];
    float* out = (float*)d_out;
    float* logits = out + 1;   // [loss, logits(256x20000), acc, inter]

    // ws layout (bytes)
    const size_t ABF_OFF  = 0;                                  // 512*512*2 = 524288
    const size_t PART_OFF = 524288;                             // 256*157*16
    const size_t SC_OFF   = PART_OFF + (size_t)B_N * NMB * 16;

    unsigned short* Abf = (unsigned short*)((char*)d_ws + ABF_OFF);
    float4* partials   = (float4*)((char*)d_ws + PART_OFF);
    float*  xlen_a     = (float*)((char*)d_ws + SC_OFF);
    float*  inv_xlen_a = xlen_a + 256;
    float*  inv_wny_a  = xlen_a + 512;
    float*  mod_val_a  = xlen_a + 768;
    float*  accums     = xlen_a + 1024;

    hipMemsetAsync(accums, 0, 3 * sizeof(float), stream);

    prep_kernel<<<B_N, 256, 0, stream>>>(emb, y, W, Abf,
                                         xlen_a, inv_xlen_a, inv_wny_a, mod_val_a);
    mfma_gemm_kernel<<<628, 256, 0, stream>>>(W, Abf, y,
                                              xlen_a, inv_xlen_a, inv_wny_a,
                                              logits, partials, accums + 2);
    reduce_kernel<<<B_N, 64, 0, stream>>>(partials, logits, y, mod_val_a,
                                          accums + 0, accums + 1);
    finalize_kernel<<<1, 1, 0, stream>>>(accums, out);
}